// Round 5
// baseline (172.394 us; speedup 1.0000x reference)
//
#include <hip/hip_runtime.h>
#include <math.h>

// EKF propagate: B=65536, nx=16, nz=8, nu=4, fp32.
//
// R9 vs R6 (61us best): wave lifetime is pinned at ~13-15us (~33k cy) across
// R4-R8 while per-wave issue is only ~5-8k cy -- waves are ~80% stalled and
// no throughput resource is saturated (HBM 21%, LDS ~12%, VALU<=53%/SIMD).
// Falsified: occupancy-cap (R5), SMEM-drain (R7), I-fetch (R8). The constant
// nobody changed: per-lane ILP = 1 element. SIMT lockstep means the 8 groups
// in a wave stall TOGETHER at every LDS join / GJ swizzle step.
// R9: each 8-lane group runs TWO independent elements (eA,eB) through the
// whole pipeline with interleaved register state -- every latency event now
// has a second independent FMA stream, compiler-scheduled at instruction
// level. VT transpose buffer is time-multiplexed A->B (DS ops are in-order
// within a wave: B's writes can't pass A's reads -> single buffer, no extra
// stalls). C/Q/A-row operands shared across both elements.
// TPB=128 (16 groups x 8 lanes), grid=2048, LDS=30976B (5 blocks/CU cap).

namespace {

constexpr int LPE    = 8;            // lanes per element-pair group
constexpr int GROUPS = 16;           // groups per block (2 elements each)
constexpr int TPB    = GROUPS * LPE; // 128 threads, 32 elements/block

// Per-group LDS layout (floats). Overlays by liveness:
//  [0,256)   VT    : V^T 16x16, time-muxed A then B     [V .. W]
//  [0,128)   TPT_A : tp_A^T 8x16   (overlay after W)    [tp .. final]
//  [128,256) TPT_B : tp_B^T 8x16
//  [256,320) SI_A  ; [320,384) SI_B : S^-1 rows 8x8
//  [384..)   VB_A: mu[16] d[16] h[8] dh[8];  [432..) VB_B same
constexpr int O_VT    = 0;
constexpr int O_TPT_A = 0;
constexpr int O_TPT_B = 128;
constexpr int O_SI_A  = 256;
constexpr int O_SI_B  = 320;
constexpr int O_MU_A  = 384, O_D_A = 400, O_H_A = 416, O_DH_A = 424;
constexpr int O_MU_B  = 432, O_D_B = 448, O_H_B = 464, O_DH_B = 472;
constexpr int GS      = 484; // 484 % 32 == 4 -> the 8 groups of a wave sit at
                             // bank offsets {0,4,...,28}: a group's b128
                             // broadcast (4 banks) tiles all 32 banks across
                             // the wave -> conflict-free; %4==0 f4-aligned

__device__ __forceinline__ float dot4(float4 a, float4 b) {
  return a.x*b.x + a.y*b.y + a.z*b.z + a.w*b.w;
}

// tanh(x) = 1 - 2/(e^{2x}+1); v_exp_f32 + v_rcp_f32. abs err ~1e-7.
__device__ __forceinline__ float tanh_fast(float x) {
  float e = __expf(2.0f * x);
  return 1.0f - 2.0f * __builtin_amdgcn_rcpf(e + 1.0f);
}

// ds_swizzle BitMode: src_lane = ((lane & 0x18) | P) -> broadcast lane P of
// each 8-lane group (offset imm must be a literal -> macro, not function).
#define SWZF(v, imm) __int_as_float(__builtin_amdgcn_ds_swizzle(__float_as_int(v), (imm)))

// Dual Gauss-Jordan elimination step for pivot P (literal): element A and B
// interleaved -- two independent swizzle->rcp->FMA chains per step.
// Invariants (per element) at entry to step P:
//   s8[j] maintained for j>=P; x8[j] maintained for j<P; x8[j>=P]=delta_tj;
//   pivot row's x8[P]==1. f-trick: for t==P, f=ps[P]-1 makes
//   s8[j]-f*(ps[j]*rp) == ps[j]*rp (normalized pivot row) -- branchless.
#define GJ_STEP2(P)                                                        \
  {                                                                        \
    float psA[8], pxA[8], psB[8], pxB[8];                                  \
    _Pragma("unroll")                                                      \
    for (int j = 0; j < 8; j++) {                                          \
      if (j >= (P)) { psA[j] = SWZF(s8A[j], (((P) << 5) | 0x18));          \
                      psB[j] = SWZF(s8B[j], (((P) << 5) | 0x18)); }        \
      else          { pxA[j] = SWZF(x8A[j], (((P) << 5) | 0x18));          \
                      pxB[j] = SWZF(x8B[j], (((P) << 5) | 0x18)); }        \
    }                                                                      \
    const float rpA = __builtin_amdgcn_rcpf(psA[(P)]);                     \
    const float rpB = __builtin_amdgcn_rcpf(psB[(P)]);                     \
    const float fA  = (t == (P)) ? (psA[(P)] - 1.0f) : s8A[(P)];           \
    const float fB  = (t == (P)) ? (psB[(P)] - 1.0f) : s8B[(P)];           \
    _Pragma("unroll")                                                      \
    for (int j = 0; j < 8; j++) {                                          \
      if (j > (P))      { s8A[j] -= fA * (psA[j] * rpA);                   \
                          s8B[j] -= fB * (psB[j] * rpB); }                 \
      else if (j < (P)) { x8A[j] -= fA * (pxA[j] * rpA);                   \
                          x8B[j] -= fB * (pxB[j] * rpB); }                 \
    }                                                                      \
    x8A[(P)] -= fA * rpA;                                                  \
    x8B[(P)] -= fB * rpB;                                                  \
  }

__global__ __launch_bounds__(TPB)
void ekf_kernel(const float* __restrict__ mu_prev,
                const float* __restrict__ Sig_prev,
                const float* __restrict__ U,
                const float* __restrict__ Z,
                const float* __restrict__ A,
                const float* __restrict__ Bm,
                const float* __restrict__ C,
                const float* __restrict__ Q,
                const float* __restrict__ R,
                float* __restrict__ mu_out,
                float* __restrict__ sig_out,
                int Btot)
{
  __shared__ float lds[GS * GROUPS];   // 30976 B -> 5 blocks/CU
  const int tid = threadIdx.x;
  const int g = tid >> 3;              // group within block
  const int t = tid & 7;               // lane within group
  int eA = blockIdx.x * (2 * GROUPS) + 2 * g;
  int eB = eA + 1;
  if (eA >= Btot) eA = Btot - 1;       // clamp; duplicate-write benign
  if (eB >= Btot) eB = Btot - 1;
  float* L = lds + g * GS;
  const int r0 = t, r1 = t + 8;        // owned matrix rows

  // ---- load Sigma rows r0,r1 for BOTH elements (issued first: latency) ----
  float sA0[16], sA1[16], sB0[16], sB1[16];
  {
    const float4* a0 = (const float4*)(Sig_prev + (size_t)eA * 256 + r0 * 16);
    const float4* a1 = (const float4*)(Sig_prev + (size_t)eA * 256 + r1 * 16);
    const float4* b0 = (const float4*)(Sig_prev + (size_t)eB * 256 + r0 * 16);
    const float4* b1 = (const float4*)(Sig_prev + (size_t)eB * 256 + r1 * 16);
    #pragma unroll
    for (int c = 0; c < 4; c++) {
      float4 va0 = a0[c], va1 = a1[c], vb0 = b0[c], vb1 = b1[c];
      sA0[4*c+0]=va0.x; sA0[4*c+1]=va0.y; sA0[4*c+2]=va0.z; sA0[4*c+3]=va0.w;
      sA1[4*c+0]=va1.x; sA1[4*c+1]=va1.y; sA1[4*c+2]=va1.z; sA1[4*c+3]=va1.w;
      sB0[4*c+0]=vb0.x; sB0[4*c+1]=vb0.y; sB0[4*c+2]=vb0.z; sB0[4*c+3]=vb0.w;
      sB1[4*c+0]=vb1.x; sB1[4*c+1]=vb1.y; sB1[4*c+2]=vb1.z; sB1[4*c+3]=vb1.w;
    }
  }

  // ---- mu_bar rows r0,r1, both elements (A-matrix rows shared/CSE'd) ----
  float mubarA0, mubarA1, dA0, dA1, mubarB0, mubarB1, dB0, dB1;
  {
    const float4* ar0 = (const float4*)(A + r0 * 16);
    const float4* ar1 = (const float4*)(A + r1 * 16);
    float4 a00=ar0[0], a01=ar0[1], a02=ar0[2], a03=ar0[3];
    float4 a10=ar1[0], a11=ar1[1], a12=ar1[2], a13=ar1[3];
    float4 bm0 = *(const float4*)(Bm + r0 * 4);
    float4 bm1 = *(const float4*)(Bm + r1 * 4);

    const float4* mA = (const float4*)(mu_prev + (size_t)eA * 16);
    float4 uA = *(const float4*)(U + (size_t)eA * 4);
    float pA0 = dot4(a00,mA[0])+dot4(a01,mA[1])+dot4(a02,mA[2])+dot4(a03,mA[3])
              + dot4(bm0,uA);
    float pA1 = dot4(a10,mA[0])+dot4(a11,mA[1])+dot4(a12,mA[2])+dot4(a13,mA[3])
              + dot4(bm1,uA);
    const float4* mB = (const float4*)(mu_prev + (size_t)eB * 16);
    float4 uB = *(const float4*)(U + (size_t)eB * 4);
    float pB0 = dot4(a00,mB[0])+dot4(a01,mB[1])+dot4(a02,mB[2])+dot4(a03,mB[3])
              + dot4(bm0,uB);
    float pB1 = dot4(a10,mB[0])+dot4(a11,mB[1])+dot4(a12,mB[2])+dot4(a13,mB[3])
              + dot4(bm1,uB);
    mubarA0 = tanh_fast(pA0); dA0 = 1.0f - mubarA0*mubarA0;
    mubarA1 = tanh_fast(pA1); dA1 = 1.0f - mubarA1*mubarA1;
    mubarB0 = tanh_fast(pB0); dB0 = 1.0f - mubarB0*mubarB0;
    mubarB1 = tanh_fast(pB1); dB1 = 1.0f - mubarB1*mubarB1;
  }
  L[O_MU_A + r0] = mubarA0; L[O_MU_A + r1] = mubarA1;
  L[O_D_A  + r0] = dA0;     L[O_D_A  + r1] = dA1;
  L[O_MU_B + r0] = mubarB0; L[O_MU_B + r1] = mubarB1;
  L[O_D_B  + r0] = dB0;     L[O_D_B  + r1] = dB1;
  __builtin_amdgcn_wave_barrier();

  // ---- h[t], dh[t] for both; keep C row t in regs (shared) ----
  float4 ct0, ct1, ct2, ct3;
  float dhlA, dhlB;
  {
    const float4* cr = (const float4*)(C + t * 16);
    ct0 = cr[0]; ct1 = cr[1]; ct2 = cr[2]; ct3 = cr[3];
    const float4* ma = (const float4*)(L + O_MU_A);
    const float4* mb = (const float4*)(L + O_MU_B);
    float phA = dot4(ct0,ma[0])+dot4(ct1,ma[1])+dot4(ct2,ma[2])+dot4(ct3,ma[3]);
    float phB = dot4(ct0,mb[0])+dot4(ct1,mb[1])+dot4(ct2,mb[2])+dot4(ct3,mb[3]);
    float hbA = tanh_fast(phA); dhlA = 1.0f - hbA * hbA;
    float hbB = tanh_fast(phB); dhlB = 1.0f - hbB * hbB;
    L[O_H_A + t] = hbA; L[O_DH_A + t] = dhlA;
    L[O_H_B + t] = hbB; L[O_DH_B + t] = dhlB;
  }
  __builtin_amdgcn_wave_barrier();
  float dhA[8], dhB[8];
  {
    float4 a0 = *(const float4*)(L + O_DH_A);
    float4 a1 = *(const float4*)(L + O_DH_A + 4);
    float4 b0 = *(const float4*)(L + O_DH_B);
    float4 b1 = *(const float4*)(L + O_DH_B + 4);
    dhA[0]=a0.x; dhA[1]=a0.y; dhA[2]=a0.z; dhA[3]=a0.w;
    dhA[4]=a1.x; dhA[5]=a1.y; dhA[6]=a1.z; dhA[7]=a1.w;
    dhB[0]=b0.x; dhB[1]=b0.y; dhB[2]=b0.z; dhB[3]=b0.w;
    dhB[4]=b1.x; dhB[5]=b1.y; dhB[6]=b1.z; dhB[7]=b1.w;
  }

  // ---- V phase, element A: V = Sig_A * A^T, scatter V^T into VT ----
  #pragma unroll
  for (int j = 0; j < 16; j++) {
    float acc0 = 0.f, acc1 = 0.f;
    #pragma unroll
    for (int k = 0; k < 16; k++) {
      float a = A[j*16 + k];                  // uniform -> s_load
      acc0 += sA0[k] * a; acc1 += sA1[k] * a;
    }
    L[O_VT + j*16 + r0] = acc0;
    L[O_VT + j*16 + r1] = acc1;
  }
  __builtin_amdgcn_wave_barrier();
  // read V_A columns r0,r1 (contiguous VT rows)
  float vcA0[16], vcA1[16];
  {
    const float4* p0 = (const float4*)(L + O_VT + r0 * 16);
    const float4* p1 = (const float4*)(L + O_VT + r1 * 16);
    #pragma unroll
    for (int c = 0; c < 4; c++) {
      float4 x0 = p0[c], x1 = p1[c];
      vcA0[4*c+0]=x0.x; vcA0[4*c+1]=x0.y; vcA0[4*c+2]=x0.z; vcA0[4*c+3]=x0.w;
      vcA1[4*c+0]=x1.x; vcA1[4*c+1]=x1.y; vcA1[4*c+2]=x1.z; vcA1[4*c+3]=x1.w;
    }
  }
  __builtin_amdgcn_wave_barrier();

  // ---- V phase, element B: reuses VT. DS ops are in-order within the wave:
  //      these writes cannot pass the vcA reads above -> no hazard. ----
  #pragma unroll
  for (int j = 0; j < 16; j++) {
    float acc0 = 0.f, acc1 = 0.f;
    #pragma unroll
    for (int k = 0; k < 16; k++) {
      float a = A[j*16 + k];                  // uniform -> s_load
      acc0 += sB0[k] * a; acc1 += sB1[k] * a;
    }
    L[O_VT + j*16 + r0] = acc0;
    L[O_VT + j*16 + r1] = acc1;
  }
  __builtin_amdgcn_wave_barrier();
  float vcB0[16], vcB1[16];
  {
    const float4* p0 = (const float4*)(L + O_VT + r0 * 16);
    const float4* p1 = (const float4*)(L + O_VT + r1 * 16);
    #pragma unroll
    for (int c = 0; c < 4; c++) {
      float4 x0 = p0[c], x1 = p1[c];
      vcB0[4*c+0]=x0.x; vcB0[4*c+1]=x0.y; vcB0[4*c+2]=x0.z; vcB0[4*c+3]=x0.w;
      vcB1[4*c+0]=x1.x; vcB1[4*c+1]=x1.y; vcB1[4*c+2]=x1.z; vcB1[4*c+3]=x1.w;
    }
  }
  __builtin_amdgcn_wave_barrier();

  // ---- W rows (W = A*V, symmetric), both elements -- 4 indep chains ----
  float sbA0[16], sbA1[16], sbB0[16], sbB1[16];
  #pragma unroll
  for (int i = 0; i < 16; i++) {
    float aA0 = 0.f, aA1 = 0.f, aB0 = 0.f, aB1 = 0.f;
    #pragma unroll
    for (int k = 0; k < 16; k++) {
      float a = A[i*16 + k];                  // uniform -> s_load
      aA0 += a * vcA0[k]; aA1 += a * vcA1[k];
      aB0 += a * vcB0[k]; aB1 += a * vcB1[k];
    }
    sbA0[i] = aA0; sbA1[i] = aA1; sbB0[i] = aB0; sbB1[i] = aB1;
  }

  // ---- Sig_bar rows: sb = R[r,:] + d_r * W[r,:] * d (both elements) ----
  {
    const float4* rr0 = (const float4*)(R + r0 * 16);
    const float4* rr1 = (const float4*)(R + r1 * 16);
    const float4* dvA = (const float4*)(L + O_D_A);
    const float4* dvB = (const float4*)(L + O_D_B);
    #pragma unroll
    for (int c = 0; c < 4; c++) {
      float4 ra = rr0[c], rb = rr1[c], da = dvA[c], db = dvB[c];
      sbA0[4*c+0] = ra.x + dA0*sbA0[4*c+0]*da.x;
      sbA0[4*c+1] = ra.y + dA0*sbA0[4*c+1]*da.y;
      sbA0[4*c+2] = ra.z + dA0*sbA0[4*c+2]*da.z;
      sbA0[4*c+3] = ra.w + dA0*sbA0[4*c+3]*da.w;
      sbA1[4*c+0] = rb.x + dA1*sbA1[4*c+0]*da.x;
      sbA1[4*c+1] = rb.y + dA1*sbA1[4*c+1]*da.y;
      sbA1[4*c+2] = rb.z + dA1*sbA1[4*c+2]*da.z;
      sbA1[4*c+3] = rb.w + dA1*sbA1[4*c+3]*da.w;
      sbB0[4*c+0] = ra.x + dB0*sbB0[4*c+0]*db.x;
      sbB0[4*c+1] = ra.y + dB0*sbB0[4*c+1]*db.y;
      sbB0[4*c+2] = ra.z + dB0*sbB0[4*c+2]*db.z;
      sbB0[4*c+3] = ra.w + dB0*sbB0[4*c+3]*db.w;
      sbB1[4*c+0] = rb.x + dB1*sbB1[4*c+0]*db.x;
      sbB1[4*c+1] = rb.y + dB1*sbB1[4*c+1]*db.y;
      sbB1[4*c+2] = rb.z + dB1*sbB1[4*c+2]*db.z;
      sbB1[4*c+3] = rb.w + dB1*sbB1[4*c+3]*db.w;
    }
  }

  // ---- tp rows = Sig_bar[r,:] C^T Dh, both elements; scatter tp^T.
  //      (TPT overlays VT: in-order DS, issued after the vcB reads.) ----
  float tpA0[8], tpA1[8], tpB0[8], tpB1[8];
  #pragma unroll
  for (int m = 0; m < 8; m++) {
    float aA0 = 0.f, aA1 = 0.f, aB0 = 0.f, aB1 = 0.f;
    #pragma unroll
    for (int k = 0; k < 16; k++) {
      float c = C[m*16 + k];                  // uniform -> s_load
      aA0 += sbA0[k] * c; aA1 += sbA1[k] * c;
      aB0 += sbB0[k] * c; aB1 += sbB1[k] * c;
    }
    tpA0[m] = aA0 * dhA[m]; tpA1[m] = aA1 * dhA[m];
    tpB0[m] = aB0 * dhB[m]; tpB1[m] = aB1 * dhB[m];
    L[O_TPT_A + m*16 + r0] = tpA0[m];
    L[O_TPT_A + m*16 + r1] = tpA1[m];
    L[O_TPT_B + m*16 + r0] = tpB0[m];
    L[O_TPT_B + m*16 + r1] = tpB1[m];
  }
  __builtin_amdgcn_wave_barrier();

  // ---- S row t = dh_t*(C[t,:] @ tp) + Q[t,:], both elements ----
  float s8A[8], s8B[8];
  {
    float4 q0 = *(const float4*)(Q + t * 8);
    float4 q1 = *(const float4*)(Q + t * 8 + 4);
    float qv[8] = {q0.x,q0.y,q0.z,q0.w,q1.x,q1.y,q1.z,q1.w};
    #pragma unroll
    for (int m = 0; m < 8; m++) {
      const float4* ta = (const float4*)(L + O_TPT_A + m * 16);  // broadcast
      const float4* tb = (const float4*)(L + O_TPT_B + m * 16);
      float accA = dot4(ct0,ta[0]) + dot4(ct1,ta[1])
                 + dot4(ct2,ta[2]) + dot4(ct3,ta[3]);
      float accB = dot4(ct0,tb[0]) + dot4(ct1,tb[1])
                 + dot4(ct2,tb[2]) + dot4(ct3,tb[3]);
      s8A[m] = accA * dhlA + qv[m];
      s8B[m] = accB * dhlB + qv[m];
    }
  }

  // ---- dual Gauss-Jordan inverses via swizzle broadcasts (two indep
  //      chains per step; S SPD -> no pivoting) ----
  float x8A[8], x8B[8];
  #pragma unroll
  for (int j = 0; j < 8; j++) {
    x8A[j] = (j == t) ? 1.0f : 0.0f;
    x8B[j] = (j == t) ? 1.0f : 0.0f;
  }
  GJ_STEP2(0) GJ_STEP2(1) GJ_STEP2(2) GJ_STEP2(3)
  GJ_STEP2(4) GJ_STEP2(5) GJ_STEP2(6) GJ_STEP2(7)

  // ---- stash S^-1 rows ----
  *((float4*)(L + O_SI_A + t*8 + 0)) = make_float4(x8A[0],x8A[1],x8A[2],x8A[3]);
  *((float4*)(L + O_SI_A + t*8 + 4)) = make_float4(x8A[4],x8A[5],x8A[6],x8A[7]);
  *((float4*)(L + O_SI_B + t*8 + 0)) = make_float4(x8B[0],x8B[1],x8B[2],x8B[3]);
  *((float4*)(L + O_SI_B + t*8 + 4)) = make_float4(x8B[4],x8B[5],x8B[6],x8B[7]);
  __builtin_amdgcn_wave_barrier();

  // ---- K rows = tp[r,:] @ Sinv, both elements ----
  float kA0[8]={0,0,0,0,0,0,0,0}, kA1[8]={0,0,0,0,0,0,0,0};
  float kB0[8]={0,0,0,0,0,0,0,0}, kB1[8]={0,0,0,0,0,0,0,0};
  #pragma unroll
  for (int m = 0; m < 8; m++) {
    float4 aa = *(const float4*)(L + O_SI_A + m*8 + 0);   // broadcast
    float4 ab = *(const float4*)(L + O_SI_A + m*8 + 4);
    float4 ba = *(const float4*)(L + O_SI_B + m*8 + 0);
    float4 bb = *(const float4*)(L + O_SI_B + m*8 + 4);
    float fA0 = tpA0[m], fA1 = tpA1[m], fB0 = tpB0[m], fB1 = tpB1[m];
    kA0[0]+=fA0*aa.x; kA0[1]+=fA0*aa.y; kA0[2]+=fA0*aa.z; kA0[3]+=fA0*aa.w;
    kA0[4]+=fA0*ab.x; kA0[5]+=fA0*ab.y; kA0[6]+=fA0*ab.z; kA0[7]+=fA0*ab.w;
    kA1[0]+=fA1*aa.x; kA1[1]+=fA1*aa.y; kA1[2]+=fA1*aa.z; kA1[3]+=fA1*aa.w;
    kA1[4]+=fA1*ab.x; kA1[5]+=fA1*ab.y; kA1[6]+=fA1*ab.z; kA1[7]+=fA1*ab.w;
    kB0[0]+=fB0*ba.x; kB0[1]+=fB0*ba.y; kB0[2]+=fB0*ba.z; kB0[3]+=fB0*ba.w;
    kB0[4]+=fB0*bb.x; kB0[5]+=fB0*bb.y; kB0[6]+=fB0*bb.z; kB0[7]+=fB0*bb.w;
    kB1[0]+=fB1*ba.x; kB1[1]+=fB1*ba.y; kB1[2]+=fB1*ba.z; kB1[3]+=fB1*ba.w;
    kB1[4]+=fB1*bb.x; kB1[5]+=fB1*bb.y; kB1[6]+=fB1*bb.z; kB1[7]+=fB1*bb.w;
  }

  // ---- mu rows, both elements ----
  {
    float4 za0 = *(const float4*)(Z + (size_t)eA * 8);
    float4 za1 = *(const float4*)(Z + (size_t)eA * 8 + 4);
    float4 ha0 = *(const float4*)(L + O_H_A);
    float4 ha1 = *(const float4*)(L + O_H_A + 4);
    float iA0=za0.x-ha0.x, iA1=za0.y-ha0.y, iA2=za0.z-ha0.z, iA3=za0.w-ha0.w;
    float iA4=za1.x-ha1.x, iA5=za1.y-ha1.y, iA6=za1.z-ha1.z, iA7=za1.w-ha1.w;
    float muA0 = mubarA0 + kA0[0]*iA0+kA0[1]*iA1+kA0[2]*iA2+kA0[3]*iA3
                         + kA0[4]*iA4+kA0[5]*iA5+kA0[6]*iA6+kA0[7]*iA7;
    float muA1 = mubarA1 + kA1[0]*iA0+kA1[1]*iA1+kA1[2]*iA2+kA1[3]*iA3
                         + kA1[4]*iA4+kA1[5]*iA5+kA1[6]*iA6+kA1[7]*iA7;
    mu_out[(size_t)eA * 16 + r0] = muA0;
    mu_out[(size_t)eA * 16 + r1] = muA1;

    float4 zb0 = *(const float4*)(Z + (size_t)eB * 8);
    float4 zb1 = *(const float4*)(Z + (size_t)eB * 8 + 4);
    float4 hb0 = *(const float4*)(L + O_H_B);
    float4 hb1 = *(const float4*)(L + O_H_B + 4);
    float iB0=zb0.x-hb0.x, iB1=zb0.y-hb0.y, iB2=zb0.z-hb0.z, iB3=zb0.w-hb0.w;
    float iB4=zb1.x-hb1.x, iB5=zb1.y-hb1.y, iB6=zb1.z-hb1.z, iB7=zb1.w-hb1.w;
    float muB0 = mubarB0 + kB0[0]*iB0+kB0[1]*iB1+kB0[2]*iB2+kB0[3]*iB3
                         + kB0[4]*iB4+kB0[5]*iB5+kB0[6]*iB6+kB0[7]*iB7;
    float muB1 = mubarB1 + kB1[0]*iB0+kB1[1]*iB1+kB1[2]*iB2+kB1[3]*iB3
                         + kB1[4]*iB4+kB1[5]*iB5+kB1[6]*iB6+kB1[7]*iB7;
    mu_out[(size_t)eB * 16 + r0] = muB0;
    mu_out[(size_t)eB * 16 + r1] = muB1;
  }

  // ---- Sig_now rows = Sig_bar - K tp^T, both elements (K S = tp exactly
  //      in real arithmetic -> equals Joseph form; fp delta ~1e-6) ----
  #pragma unroll
  for (int m = 0; m < 8; m++) {
    const float4* ta = (const float4*)(L + O_TPT_A + m * 16);  // broadcast
    const float4* tb = (const float4*)(L + O_TPT_B + m * 16);
    float4 a0 = ta[0], a1 = ta[1], a2 = ta[2], a3 = ta[3];
    float4 b0 = tb[0], b1 = tb[1], b2 = tb[2], b3 = tb[3];
    float mA0 = kA0[m], mA1 = kA1[m], mB0 = kB0[m], mB1 = kB1[m];
    sbA0[0] -=mA0*a0.x; sbA0[1] -=mA0*a0.y; sbA0[2] -=mA0*a0.z; sbA0[3] -=mA0*a0.w;
    sbA0[4] -=mA0*a1.x; sbA0[5] -=mA0*a1.y; sbA0[6] -=mA0*a1.z; sbA0[7] -=mA0*a1.w;
    sbA0[8] -=mA0*a2.x; sbA0[9] -=mA0*a2.y; sbA0[10]-=mA0*a2.z; sbA0[11]-=mA0*a2.w;
    sbA0[12]-=mA0*a3.x; sbA0[13]-=mA0*a3.y; sbA0[14]-=mA0*a3.z; sbA0[15]-=mA0*a3.w;
    sbA1[0] -=mA1*a0.x; sbA1[1] -=mA1*a0.y; sbA1[2] -=mA1*a0.z; sbA1[3] -=mA1*a0.w;
    sbA1[4] -=mA1*a1.x; sbA1[5] -=mA1*a1.y; sbA1[6] -=mA1*a1.z; sbA1[7] -=mA1*a1.w;
    sbA1[8] -=mA1*a2.x; sbA1[9] -=mA1*a2.y; sbA1[10]-=mA1*a2.z; sbA1[11]-=mA1*a2.w;
    sbA1[12]-=mA1*a3.x; sbA1[13]-=mA1*a3.y; sbA1[14]-=mA1*a3.z; sbA1[15]-=mA1*a3.w;
    sbB0[0] -=mB0*b0.x; sbB0[1] -=mB0*b0.y; sbB0[2] -=mB0*b0.z; sbB0[3] -=mB0*b0.w;
    sbB0[4] -=mB0*b1.x; sbB0[5] -=mB0*b1.y; sbB0[6] -=mB0*b1.z; sbB0[7] -=mB0*b1.w;
    sbB0[8] -=mB0*b2.x; sbB0[9] -=mB0*b2.y; sbB0[10]-=mB0*b2.z; sbB0[11]-=mB0*b2.w;
    sbB0[12]-=mB0*b3.x; sbB0[13]-=mB0*b3.y; sbB0[14]-=mB0*b3.z; sbB0[15]-=mB0*b3.w;
    sbB1[0] -=mB1*b0.x; sbB1[1] -=mB1*b0.y; sbB1[2] -=mB1*b0.z; sbB1[3] -=mB1*b0.w;
    sbB1[4] -=mB1*b1.x; sbB1[5] -=mB1*b1.y; sbB1[6] -=mB1*b1.z; sbB1[7] -=mB1*b1.w;
    sbB1[8] -=mB1*b2.x; sbB1[9] -=mB1*b2.y; sbB1[10]-=mB1*b2.z; sbB1[11]-=mB1*b2.w;
    sbB1[12]-=mB1*b3.x; sbB1[13]-=mB1*b3.y; sbB1[14]-=mB1*b3.z; sbB1[15]-=mB1*b3.w;
  }
  {
    float4* oA0 = (float4*)(sig_out + (size_t)eA * 256 + r0 * 16);
    float4* oA1 = (float4*)(sig_out + (size_t)eA * 256 + r1 * 16);
    oA0[0] = make_float4(sbA0[0],  sbA0[1],  sbA0[2],  sbA0[3]);
    oA0[1] = make_float4(sbA0[4],  sbA0[5],  sbA0[6],  sbA0[7]);
    oA0[2] = make_float4(sbA0[8],  sbA0[9],  sbA0[10], sbA0[11]);
    oA0[3] = make_float4(sbA0[12], sbA0[13], sbA0[14], sbA0[15]);
    oA1[0] = make_float4(sbA1[0],  sbA1[1],  sbA1[2],  sbA1[3]);
    oA1[1] = make_float4(sbA1[4],  sbA1[5],  sbA1[6],  sbA1[7]);
    oA1[2] = make_float4(sbA1[8],  sbA1[9],  sbA1[10], sbA1[11]);
    oA1[3] = make_float4(sbA1[12], sbA1[13], sbA1[14], sbA1[15]);
    float4* oB0 = (float4*)(sig_out + (size_t)eB * 256 + r0 * 16);
    float4* oB1 = (float4*)(sig_out + (size_t)eB * 256 + r1 * 16);
    oB0[0] = make_float4(sbB0[0],  sbB0[1],  sbB0[2],  sbB0[3]);
    oB0[1] = make_float4(sbB0[4],  sbB0[5],  sbB0[6],  sbB0[7]);
    oB0[2] = make_float4(sbB0[8],  sbB0[9],  sbB0[10], sbB0[11]);
    oB0[3] = make_float4(sbB0[12], sbB0[13], sbB0[14], sbB0[15]);
    oB1[0] = make_float4(sbB1[0],  sbB1[1],  sbB1[2],  sbB1[3]);
    oB1[1] = make_float4(sbB1[4],  sbB1[5],  sbB1[6],  sbB1[7]);
    oB1[2] = make_float4(sbB1[8],  sbB1[9],  sbB1[10], sbB1[11]);
    oB1[3] = make_float4(sbB1[12], sbB1[13], sbB1[14], sbB1[15]);
  }
}

} // namespace

extern "C" void kernel_launch(void* const* d_in, const int* in_sizes, int n_in,
                              void* d_out, int out_size, void* d_ws, size_t ws_size,
                              hipStream_t stream)
{
  const float* mu_prev = (const float*)d_in[0];
  const float* Sigma   = (const float*)d_in[1];
  const float* u       = (const float*)d_in[2];
  const float* z       = (const float*)d_in[3];
  const float* A       = (const float*)d_in[4];
  const float* Bm      = (const float*)d_in[5];
  const float* C       = (const float*)d_in[6];
  const float* Q       = (const float*)d_in[7];
  const float* R       = (const float*)d_in[8];

  const int Btot = in_sizes[0] / 16;                 // B = 65536
  float* mu_out  = (float*)d_out;
  float* sig_out = (float*)d_out + (size_t)Btot * 16;

  const int EPB = 2 * GROUPS;                        // 32 elements/block
  const int grid = (Btot + EPB - 1) / EPB;           // 2048 blocks x 128 thr
  ekf_kernel<<<grid, TPB, 0, stream>>>(mu_prev, Sigma, u, z, A, Bm, C, Q, R,
                                       mu_out, sig_out, Btot);
}